// Round 10
// baseline (192.137 us; speedup 1.0000x reference)
//
#include <hip/hip_runtime.h>

#define DIM   256
#define NE    8192
#define NTOK  16384

// d_out flat offsets (floats)
#define OFF_Q    0
#define OFF_DIFF 4194304
#define OFF_IND  4194305
#define OFF_OH   4210689
#define OFF_ES   4218881

#define NCAND 32      // keys per token: 4 nbg x 2 wn x top-4 (in-screen reduced)
#define CAP   1024    // scatter-list capacity per code (exact fallback past CAP)
#define CHUNK 64      // tokens per embed_sum work item (one wave each)
#define DESC_MAX 8448 // <= nonzero codes (8192) + NTOK/CHUNK (256)

typedef __attribute__((ext_vector_type(8))) short short8;
typedef __attribute__((ext_vector_type(4))) float floatx4;

__device__ inline unsigned umin2(unsigned a, unsigned b) { return a < b ? a : b; }
__device__ inline unsigned umax2(unsigned a, unsigned b) { return a > b ? a : b; }

__device__ inline void gl_lds16(const void* g, void* l) {
    __builtin_amdgcn_global_load_lds(
        (const __attribute__((address_space(1))) unsigned int*)g,
        (__attribute__((address_space(3))) unsigned int*)l, 16, 0, 0);
}

__device__ inline unsigned short b16rn(float f) {
    unsigned u = __float_as_uint(f);
    unsigned r = (u + 0x7fffu + ((u >> 16) & 1u)) >> 16;
    return (unsigned short)r;
}

// ---------------------------------------------------------------------------
// Xbf[m][d] = bf16(x[m][d])  (row-major; A-fragments read directly from this)
__global__ void convert_x_kernel(const float* __restrict__ x,
                                 unsigned short* __restrict__ Xbf) {
    int i = blockIdx.x * 256 + threadIdx.x;   // float4 index
    float4 v = ((const float4*)x)[i];
    ushort4 h;
    h.x = b16rn(v.x); h.y = b16rn(v.y); h.z = b16rn(v.z); h.w = b16rn(v.w);
    ((ushort4*)Xbf)[i] = h;
}

// ---------------------------------------------------------------------------
// convert_e: embed -> (a) EbfT tiled bf16(-512*e) in the EXACT order the
// screen's gl_lds staging + fragment reads want: [tile128][kb8][quad4][n128][8],
// (b) embedT fp32 [n][d] for rescore/gather, (c) e2 / es2 per code.
__global__ void convert_e_kernel(const float* __restrict__ embed,
                                 unsigned short* __restrict__ EbfT,
                                 float* __restrict__ embedT,
                                 float* __restrict__ e2,
                                 float* __restrict__ es2) {
    __shared__ __align__(16) float t2[32][DIM + 4];
    __shared__ float red[32][8];
    int c0 = blockIdx.x * 32;
    int tid = threadIdx.x;
    for (int t = 0; t < 32; ++t) {
        int i = t * 256 + tid;
        int d = i >> 5, c = i & 31;
        t2[c][d] = embed[(size_t)d * NE + c0 + c];
    }
    __syncthreads();
    for (int t = 0; t < 8; ++t) {
        int i = t * 256 + tid;          // 0..2047 float4 units
        int c = i >> 6, dq = i & 63;    // code-local, k-quad (k = 4*dq)
        float4 v = *(const float4*)&t2[c][dq * 4];
        *(float4*)&embedT[(size_t)(c0 + c) * DIM + dq * 4] = v;
        ushort4 h;
        h.x = b16rn(-512.0f * v.x); h.y = b16rn(-512.0f * v.y);
        h.z = b16rn(-512.0f * v.z); h.w = b16rn(-512.0f * v.w);
        int C = c0 + c;
        int nb = C >> 7, n = C & 127;
        size_t off = (size_t)nb * 32768 + (size_t)(dq >> 3) * 4096 +
                     (size_t)((dq >> 1) & 3) * 1024 + (size_t)n * 8 + (dq & 1) * 4;
        *(ushort4*)&EbfT[off] = h;
    }
    // e2: 8 threads per code, 32 d each
    {
        int c = tid >> 3, seg = tid & 7;
        float s = 0.f;
        for (int d = seg * 32; d < seg * 32 + 32; ++d)
            s = fmaf(t2[c][d], t2[c][d], s);
        red[c][seg] = s;
    }
    __syncthreads();
    if (tid < 32) {
        float s = 0.f;
        for (int j = 0; j < 8; ++j) s += red[tid][j];
        e2[c0 + tid] = s;
        es2[c0 + tid] = 256.0f * (512.0f + s);
    }
}

// ---------------------------------------------------------------------------
// Screening GEMM, FAT-PHASE variant: 128-code subtiles (64 KB) double-buffered
// in 128 KB dynamic LDS, ONE 512-thread block per CU (grid 256). Phase count
// halves (16 barriers vs 32) and the 2-block convoy disappears; the measured
// ~3000cyc/phase fixed overhead (barrier skew + vmcnt drain) amortizes over
// 2x the MFMA. Waves/SIMD unchanged (2). Staging layout == EbfT tile layout
// (64KB contiguous per subtile). Per-(nbg,wn) top-4 reduced in-register at
// the end -> cand is 32 keys/token.
__global__ __launch_bounds__(512, 2) void dist_screen_kernel(
    const unsigned short* __restrict__ Xbf,
    const unsigned short* __restrict__ EbfT,
    const float* __restrict__ es2,
    unsigned int* __restrict__ cand) {
    extern __shared__ __align__(16) unsigned short Bs[];   // 2 x 64 KB

    const int tid  = threadIdx.x;
    const int lane = tid & 63;
    const int wid  = tid >> 6;                   // 0..7
    const int wm   = wid >> 1, wn = wid & 1;     // wm 0..3 token-groups
    const int col  = lane & 15, quad = lane >> 4;
    const int bid  = blockIdx.x;                 // 0..255, 1 block/CU
    const int r8   = bid & 7;
    const int nbg  = r8 & 3;                     // pinned per XCD
    const int m0   = ((bid >> 3) * 2 + (r8 >> 2)) * 256;  // bijective 256-token tile

    // preload all A fragments: af[mi][kb] (128 VGPRs), reused for 16 n-tiles
    short8 af[4][8];
#pragma unroll
    for (int mi = 0; mi < 4; ++mi) {
        const unsigned short* base =
            Xbf + (size_t)(m0 + wm * 64 + mi * 16 + col) * DIM + quad * 8;
#pragma unroll
        for (int kb = 0; kb < 8; ++kb)
            af[mi][kb] = *(const short8*)(base + kb * 32);
    }

    unsigned b1[16], b2[16];
#pragma unroll
    for (int i = 0; i < 16; ++i) { b1[i] = 0xFFFFFFFFu; b2[i] = 0xFFFFFFFFu; }

    // staging: one EbfT tile128 (64 KB) is contiguous and == LDS layout.
    // thread stages bytes [tid*16 + i*8192), i=0..7  (512 thr x 16B = 8KB/i).
    const char* gbase = (const char*)EbfT + (size_t)nbg * 16 * 65536 + tid * 16;
    char* ldst0 = (char*)Bs + tid * 16;

#define STAGE(st, b)                                                          \
    {                                                                         \
        const char* s_ = gbase + (size_t)(st) * 65536;                        \
        char* d_ = ldst0 + (b) * 65536;                                       \
        _Pragma("unroll")                                                     \
        for (int i_ = 0; i_ < 8; ++i_)                                        \
            gl_lds16(s_ + i_ * 8192, d_ + i_ * 8192);                         \
    }

    STAGE(0, 0);
    __syncthreads();
    int cur = 0;

    for (int st = 0; st < 16; ++st) {
        if (st < 15) STAGE(st + 1, cur ^ 1);   // prefetch next tile (other buf)

        const int n0 = nbg * 2048 + st * 128;
        const unsigned short* B = &Bs[cur * 32768];
#pragma unroll
        for (int nh = 0; nh < 2; ++nh) {       // 2 ni-halves (caps VGPRs)
            const int n_a = wn * 64 + nh * 32 + col;
            const int n_b = n_a + 16;
            float e0 = es2[n0 + n_a];
            float e1 = es2[n0 + n_b];
            floatx4 acc[4][2];
#pragma unroll
            for (int mi = 0; mi < 4; ++mi) {
                acc[mi][0] = (floatx4)e0;      // C-in carries ||e||^2 term
                acc[mi][1] = (floatx4)e1;
            }
#pragma unroll
            for (int kb = 0; kb < 8; ++kb) {
                // 16 consecutive cols x 16B -> conflict-free b128
                short8 bf0 = *(const short8*)&B[kb * 4096 + quad * 1024 + n_a * 8];
                short8 bf1 = *(const short8*)&B[kb * 4096 + quad * 1024 + n_b * 8];
#pragma unroll
                for (int mi = 0; mi < 4; ++mi) {
                    acc[mi][0] = __builtin_amdgcn_mfma_f32_16x16x32_bf16(
                        af[mi][kb], bf0, acc[mi][0], 0, 0, 0);
                    acc[mi][1] = __builtin_amdgcn_mfma_f32_16x16x32_bf16(
                        af[mi][kb], bf1, acc[mi][1], 0, 0, 0);
                }
            }
#pragma unroll
            for (int nj = 0; nj < 2; ++nj) {
                unsigned idxc = (unsigned)(n0 + wn * 64 + nh * 32 + nj * 16 + col);
#pragma unroll
                for (int mi = 0; mi < 4; ++mi)
#pragma unroll
                    for (int r = 0; r < 4; ++r) {
                        unsigned key = ((unsigned)acc[mi][nj][r] << 13) + idxc;
                        int s = mi * 4 + r;
                        unsigned lo = umin2(key, b1[s]);
                        unsigned hi = umax2(key, b1[s]);
                        b1[s] = lo;
                        b2[s] = umin2(hi, b2[s]);   // -> v_med3_u32
                    }
            }
        }
        __syncthreads();                       // staged(st+1) landed; reads done
        cur ^= 1;
    }
#undef STAGE

    // cross-col top-4 reduce per (token, nbg, wn); col 0 writes 4 keys
#pragma unroll
    for (int s = 0; s < 16; ++s) {
        unsigned v1 = b1[s], v2 = b2[s];
        unsigned v3 = 0xFFFFFFFFu, v4 = 0xFFFFFFFFu;
#pragma unroll
        for (int m = 1; m < 16; m <<= 1) {
            unsigned p[4];
            p[0] = (unsigned)__shfl_xor((int)v1, m);
            p[1] = (unsigned)__shfl_xor((int)v2, m);
            p[2] = (unsigned)__shfl_xor((int)v3, m);
            p[3] = (unsigned)__shfl_xor((int)v4, m);
#pragma unroll
            for (int j = 0; j < 4; ++j) {
                unsigned k = p[j], t;
                t = umax2(k, v1); v1 = umin2(k, v1); k = t;
                t = umax2(k, v2); v2 = umin2(k, v2); k = t;
                t = umax2(k, v3); v3 = umin2(k, v3); k = t;
                v4 = umin2(k, v4);
            }
        }
        if (col == 0) {
            int mi = s >> 2, r = s & 3;
            int token = m0 + wm * 64 + mi * 16 + quad * 4 + r;
            uint4 o; o.x = v1; o.y = v2; o.z = v3; o.w = v4;
            *(uint4*)&cand[(size_t)token * NCAND + nbg * 8 + wn * 4] = o;
        }
    }
}

// ---------------------------------------------------------------------------
// Fused exact fp32 rescore + quantize gather + cursor scatter.
// cand is 32 keys/token (128B): lane&31 holds one key; upper half masked.
// GROUP-PARALLEL rescore: each 16-lane group scores its own candidate.
__global__ __launch_bounds__(256) void finalize_kernel(
    const float* __restrict__ x, const float* __restrict__ embedT,
    const float* __restrict__ e2,
    const unsigned int* __restrict__ cand,
    float* __restrict__ out,
    unsigned int* __restrict__ cnt,
    unsigned short* __restrict__ slots,
    float* __restrict__ diffp) {
    __shared__ float partial[4];
    int tid = threadIdx.x, w = tid >> 6, lane = tid & 63;
    int l16 = lane & 15, grp = lane >> 4;
    int token = blockIdx.x * 4 + w;

    float4 xv = *(const float4*)&x[(size_t)token * DIM + lane * 4];
    // replicated x row per 16-lane group (L1-hot reload of the same 1KB)
    float4 xg[4];
#pragma unroll
    for (int q = 0; q < 4; ++q)
        xg[q] = *(const float4*)&x[(size_t)token * DIM + q * 64 + l16 * 4];

    float x2 = xv.x * xv.x + xv.y * xv.y + xv.z * xv.z + xv.w * xv.w;
    unsigned kl = cand[(size_t)token * NCAND + (lane & 31)];
    if (lane >= 32) kl = 0xFFFFFFFFu;    // dedupe the replicated half
    unsigned g = kl;
#pragma unroll
    for (int m = 1; m < 64; m <<= 1) {
        x2 += __shfl_xor(x2, m);
        g = umin2(g, (unsigned)__shfl_xor((int)g, m));
    }
    const unsigned thr = g + (384u << 13);   // margin 1.5 in true-dist units

    float bd = 3.4e38f; int bk = 0x7fffffff;
    unsigned long long mask = __ballot(kl <= thr);
    while (mask) {
        int kk[4];
#pragma unroll
        for (int g2 = 0; g2 < 4; ++g2) {
            int l = mask ? (__ffsll(mask) - 1) : 0;
            int kv = __shfl((int)kl, l) & 8191;
            kk[g2] = mask ? kv : -1;
            mask &= mask - 1;
        }
        int myk = kk[grp];
        int kc = myk < 0 ? 0 : myk;
        const float* er = &embedT[(size_t)kc * DIM];
        float p = 0.f;
#pragma unroll
        for (int q = 0; q < 4; ++q) {
            float4 ev = *(const float4*)&er[q * 64 + l16 * 4];
            p = fmaf(xg[q].x, ev.x, p);
            p = fmaf(xg[q].y, ev.y, p);
            p = fmaf(xg[q].z, ev.z, p);
            p = fmaf(xg[q].w, ev.w, p);
        }
#pragma unroll
        for (int m = 1; m < 16; m <<= 1) p += __shfl_xor(p, m);
        float dg = (myk >= 0) ? (e2[kc] - 2.0f * p) : 3.4e38f;
#pragma unroll
        for (int g2 = 0; g2 < 4; ++g2) {
            float d2 = __shfl(dg, g2 * 16);
            int k2 = kk[g2];
            if (k2 >= 0 && (d2 < bd || (d2 == bd && k2 < bk))) {
                bd = d2; bk = k2;
            }
        }
    }
    // winner row gather (1KB, L2-hot from the rescore) + outputs
    float4 bq = *(const float4*)&embedT[(size_t)bk * DIM + lane * 4];
    *(float4*)&out[OFF_Q + (size_t)token * DIM + lane * 4] = bq;
    if (lane == 0) {
        out[OFF_IND + token] = (float)bk;
        unsigned pos = atomicAdd(&cnt[bk], 1u);
        if (pos < CAP) slots[(size_t)bk * CAP + pos] = (unsigned short)token;
        partial[w] = x2 + bd;
    }
    __syncthreads();
    if (tid == 0)
        diffp[blockIdx.x] =
            partial[0] + partial[1] + partial[2] + partial[3];
}

// ---------------------------------------------------------------------------
// build_desc: one chunk descriptor per CHUNK tokens of a code, wave-batched
// allocation (1 same-address atomic per WAVE = 128 total, vs 8400 in-line).
__global__ __launch_bounds__(256) void build_desc_kernel(
    const unsigned int* __restrict__ cnt,
    unsigned int* __restrict__ ndesc,
    unsigned int* __restrict__ desc) {
    int k = blockIdx.x * 256 + threadIdx.x;
    int lane = threadIdx.x & 63;
    unsigned n = cnt[k];
    unsigned nc = (n > CAP) ? 1u : (n + CHUNK - 1) >> 6;   // chunks for this code
    unsigned pfx = nc;
#pragma unroll
    for (int m = 1; m < 64; m <<= 1) {
        unsigned t = __shfl_up(pfx, m);
        if (lane >= m) pfx += t;
    }
    unsigned base = 0;
    if (lane == 63) base = atomicAdd(ndesc, pfx);
    base = __shfl(base, 63);
    unsigned off = base + pfx - nc;
    for (unsigned j = 0; j < nc; ++j)
        desc[off + j] = (unsigned)k | (j << 13);
}

// ---------------------------------------------------------------------------
// embed_sum: one WAVE per 64-token chunk descriptor (balanced). 8-way ILP:
// 8 slot ids per uint4, 8 independent coalesced 1KB x-row loads in flight.
__global__ __launch_bounds__(256) void embed_sum_kernel(
    const float* __restrict__ x,
    const unsigned int* __restrict__ cnt,
    const unsigned short* __restrict__ slots,
    const unsigned int* __restrict__ ndesc,
    const unsigned int* __restrict__ desc,
    const float* __restrict__ out_ind,
    float* __restrict__ esT) {
    int tid = threadIdx.x, w = tid >> 6, lane = tid & 63;
    unsigned wv = blockIdx.x * 4 + w;
    if (wv >= *ndesc) return;
    unsigned dsc = desc[wv];
    int k = dsc & 8191;
    int j = dsc >> 13;
    unsigned n = cnt[k];
    float ax = 0.f, ay = 0.f, az = 0.f, aw = 0.f;

    if (n > CAP) {           // pathological overflow: exact full scan (j==0 only)
        for (int tok = 0; tok < NTOK; ++tok)
            if ((int)out_ind[tok] == k) {
                float4 v = *(const float4*)&x[(size_t)tok * DIM + lane * 4];
                ax += v.x; ay += v.y; az += v.z; aw += v.w;
            }
        *(float4*)&esT[(size_t)k * DIM + lane * 4] = make_float4(ax, ay, az, aw);
        return;
    }

    int base = j * CHUNK;
    int nt = (int)n - base; if (nt > CHUNK) nt = CHUNK;
    const unsigned short* sl = &slots[(size_t)k * CAP + base];
    for (int gr = 0; gr < CHUNK; gr += 8) {
        if (gr >= nt) break;
        uint4 sv = *(const uint4*)(sl + gr);        // 8 slot ids, 16B aligned
        unsigned id[8] = {sv.x & 0xffffu, sv.x >> 16, sv.y & 0xffffu, sv.y >> 16,
                          sv.z & 0xffffu, sv.z >> 16, sv.w & 0xffffu, sv.w >> 16};
        float4 v[8];
#pragma unroll
        for (int i = 0; i < 8; ++i) {
            unsigned tok = (gr + i < nt) ? id[i] : id[0];  // clamp tail in-bounds
            v[i] = *(const float4*)&x[(size_t)tok * DIM + lane * 4];
        }
#pragma unroll
        for (int i = 0; i < 8; ++i)
            if (gr + i < nt) { ax += v[i].x; ay += v[i].y; az += v[i].z; aw += v[i].w; }
    }

    float* dst = &esT[(size_t)k * DIM + lane * 4];
    if (n <= CHUNK) {
        *(float4*)dst = make_float4(ax, ay, az, aw);
    } else {
        atomicAdd(dst + 0, ax); atomicAdd(dst + 1, ay);
        atomicAdd(dst + 2, az); atomicAdd(dst + 3, aw);
    }
}

// ---------------------------------------------------------------------------
// es_out: transposed ES write + OH from cnt + DIFF reduction (block 0).
__global__ void es_out_kernel(const float* __restrict__ esT,
                              const unsigned int* __restrict__ cnt,
                              const float* __restrict__ diffp,
                              float* __restrict__ out) {
    __shared__ __align__(16) float t2[32][DIM + 4];
    __shared__ float rsum[256];
    int k0 = blockIdx.x * 32;
    int tid = threadIdx.x;
    for (int t = 0; t < 8; ++t) {
        int i = t * 256 + tid;          // float4 units over 32x256
        int k = i >> 6, dq = i & 63;
        float4 v = ((const float4*)esT)[(size_t)(k0 + k) * 64 + dq];
        *(float4*)&t2[k][dq * 4] = v;
    }
    __syncthreads();
    for (int t = 0; t < 32; ++t) {
        int i = t * 256 + tid;          // 8192 cells
        int d = i >> 5, c = i & 31;
        out[OFF_ES + (size_t)d * NE + k0 + c] = t2[c][d];
    }
    if (tid < 32) out[OFF_OH + k0 + tid] = (float)cnt[k0 + tid];
    if (blockIdx.x == 0) {              // DIFF: reduce 4096 per-block partials
        float s = 0.f;
        for (int i = tid; i < NTOK / 4; i += 256) s += diffp[i];
        rsum[tid] = s;
        __syncthreads();
        for (int st = 128; st > 0; st >>= 1) {
            if (tid < st) rsum[tid] += rsum[tid + st];
            __syncthreads();
        }
        if (tid == 0) out[OFF_DIFF] = rsum[0] * (1.0f / 4194304.0f);
    }
}

// ===========================================================================
extern "C" void kernel_launch(void* const* d_in, const int* in_sizes, int n_in,
                              void* d_out, int out_size, void* d_ws, size_t ws_size,
                              hipStream_t stream) {
    const float* x     = (const float*)d_in[0];
    const float* embed = (const float*)d_in[1];
    float* out = (float*)d_out;

    // ws layout (~40 MB). esT ALIASES Xbf (both exactly 8.4 MB): Xbf is dead
    // after dist_screen; the esT memset is enqueued after finalize in stream
    // order, so no hazard.
    char* p = (char*)d_ws;
    unsigned short* Xbf  = (unsigned short*)p;  p += (size_t)NTOK * DIM * 2;    // 8.4 MB
    float* esT = (float*)Xbf;                                                   // alias
    unsigned short* EbfT = (unsigned short*)p;  p += (size_t)NE * DIM * 2;      // 4.2 MB (tiled)
    float* embedT = (float*)p;                  p += (size_t)NE * DIM * 4;      // 8.4 MB
    float* e2     = (float*)p;                  p += (size_t)NE * 4;
    float* es2    = (float*)p;                  p += (size_t)NE * 4;
    unsigned int* cand = (unsigned int*)p;      p += (size_t)NTOK * NCAND * 4;  // 2 MB
    unsigned int* cnt  = (unsigned int*)p;      p += (size_t)NE * 4;            // 32 KB
    unsigned int* ndesc = (unsigned int*)p;     p += 64;                        // (memset w/ cnt)
    unsigned int* desc = (unsigned int*)p;      p += (size_t)(DESC_MAX + 64) * 4;
    float* diffp = (float*)p;                   p += (size_t)(NTOK / 4) * 4;    // 16 KB
    unsigned short* slots = (unsigned short*)p; p += (size_t)NE * CAP * 2;      // 16.8 MB

    // allow 128 KB dynamic LDS for the fat-phase screen (immediate API, not a
    // stream op -> graph-capture safe; called every launch, cheap)
    hipFuncSetAttribute(reinterpret_cast<const void*>(dist_screen_kernel),
                        hipFuncAttributeMaxDynamicSharedMemorySize, 131072);

    // cnt + ndesc zeroed; d_out header needs no memset (DIFF/IND/OH/Q/ES all
    // fully written every launch: IND by finalize, OH+DIFF by es_out).
    hipMemsetAsync(cnt, 0, (size_t)NE * 4 + 64, stream);

    convert_x_kernel<<<(NTOK * DIM / 4) / 256, 256, 0, stream>>>(x, Xbf);
    convert_e_kernel<<<NE / 32, 256, 0, stream>>>(embed, EbfT, embedT, e2, es2);
    dist_screen_kernel<<<256, 512, 131072, stream>>>(Xbf, EbfT, es2, cand);
    finalize_kernel<<<NTOK / 4, 256, 0, stream>>>(
        x, embedT, e2, cand, out, cnt, slots, diffp);
    build_desc_kernel<<<NE / 256, 256, 0, stream>>>(cnt, ndesc, desc);
    // Xbf dead from here; zero it for use as esT accumulator
    hipMemsetAsync(esT, 0, (size_t)NE * DIM * 4, stream);
    embed_sum_kernel<<<DESC_MAX / 4, 256, 0, stream>>>(
        x, cnt, slots, ndesc, desc, out + OFF_IND, esT);
    es_out_kernel<<<NE / 32, 256, 0, stream>>>(esT, cnt, diffp, out);
}

// Round 11
// 184.360 us; speedup vs baseline: 1.0422x; 1.0422x over previous
//
#include <hip/hip_runtime.h>

#define DIM   256
#define NE    8192
#define NTOK  16384

// d_out flat offsets (floats)
#define OFF_Q    0
#define OFF_DIFF 4194304
#define OFF_IND  4194305
#define OFF_OH   4210689
#define OFF_ES   4218881

#define NCAND 256     // keys per token: 4 nbg x 2 wn x 16 col x top-2
#define CAP   1024    // scatter-list capacity per code (exact fallback past CAP)
#define CHUNK 64      // tokens per embed_sum work item (one wave each)
#define DESC_MAX 8448 // = codes (8192, every code >=1 desc) + NTOK/CHUNK (256)

typedef __attribute__((ext_vector_type(8))) short short8;
typedef __attribute__((ext_vector_type(4))) float floatx4;

__device__ inline unsigned umin2(unsigned a, unsigned b) { return a < b ? a : b; }
__device__ inline unsigned umax2(unsigned a, unsigned b) { return a > b ? a : b; }

__device__ inline void gl_lds16(const void* g, void* l) {
    __builtin_amdgcn_global_load_lds(
        (const __attribute__((address_space(1))) unsigned int*)g,
        (__attribute__((address_space(3))) unsigned int*)l, 16, 0, 0);
}

__device__ inline unsigned short b16rn(float f) {
    unsigned u = __float_as_uint(f);
    unsigned r = (u + 0x7fffu + ((u >> 16) & 1u)) >> 16;
    return (unsigned short)r;
}

// ---------------------------------------------------------------------------
// Fused conversion kernel (saves one dispatch):
//   blocks [0, 4096):   Xbf[m][d] = bf16(x[m][d])
//   blocks [4096, 4352): embed -> EbfT tiled bf16(-512e) + embedT + e2/es2
__global__ void convert_kernel(const float* __restrict__ x,
                               unsigned short* __restrict__ Xbf,
                               const float* __restrict__ embed,
                               unsigned short* __restrict__ EbfT,
                               float* __restrict__ embedT,
                               float* __restrict__ e2,
                               float* __restrict__ es2) {
    __shared__ __align__(16) float t2[32][DIM + 4];
    __shared__ float red[32][8];
    int tid = threadIdx.x;

    if (blockIdx.x < 4096) {               // ---- convert_x part
        int i = blockIdx.x * 256 + tid;    // float4 index
        float4 v = ((const float4*)x)[i];
        ushort4 h;
        h.x = b16rn(v.x); h.y = b16rn(v.y); h.z = b16rn(v.z); h.w = b16rn(v.w);
        ((ushort4*)Xbf)[i] = h;
        return;
    }
    // ---- convert_e part
    int c0 = (blockIdx.x - 4096) * 32;
    for (int t = 0; t < 32; ++t) {
        int i = t * 256 + tid;
        int d = i >> 5, c = i & 31;
        t2[c][d] = embed[(size_t)d * NE + c0 + c];
    }
    __syncthreads();
    for (int t = 0; t < 8; ++t) {
        int i = t * 256 + tid;          // 0..2047 float4 units
        int c = i >> 6, dq = i & 63;    // code-local, k-quad (k = 4*dq)
        float4 v = *(const float4*)&t2[c][dq * 4];
        *(float4*)&embedT[(size_t)(c0 + c) * DIM + dq * 4] = v;
        ushort4 h;
        h.x = b16rn(-512.0f * v.x); h.y = b16rn(-512.0f * v.y);
        h.z = b16rn(-512.0f * v.z); h.w = b16rn(-512.0f * v.w);
        int C = c0 + c;
        int nb = C >> 7, n = C & 127;
        size_t off = (size_t)nb * 32768 + (size_t)(dq >> 3) * 4096 +
                     (size_t)((dq >> 1) & 3) * 1024 + (size_t)n * 8 + (dq & 1) * 4;
        *(ushort4*)&EbfT[off] = h;
    }
    // e2: 8 threads per code, 32 d each
    {
        int c = tid >> 3, seg = tid & 7;
        float s = 0.f;
        for (int d = seg * 32; d < seg * 32 + 32; ++d)
            s = fmaf(t2[c][d], t2[c][d], s);
        red[c][seg] = s;
    }
    __syncthreads();
    if (tid < 32) {
        float s = 0.f;
        for (int j = 0; j < 8; ++j) s += red[tid][j];
        e2[c0 + tid] = s;
        es2[c0 + tid] = 256.0f * (512.0f + s);
    }
}

// ---------------------------------------------------------------------------
// Screening GEMM (best-measured r7 config, byte-identical): 64-code sub-tiles
// double-buffered in 2 x 32KB LDS, 128-token blocks, XCD-pinned nbg, C-in
// carries ||e||^2. This 2-barrier structure measures ~930 TF effective =
// its documented structural ceiling; 5 perturbations (r6-r10) all confirmed.
__global__ __launch_bounds__(256, 2) void dist_screen_kernel(
    const unsigned short* __restrict__ Xbf,
    const unsigned short* __restrict__ EbfT,
    const float* __restrict__ es2,
    unsigned int* __restrict__ cand) {
    __shared__ __align__(16) unsigned short Bs[2][16384];   // 2 x 32 KB

    const int tid  = threadIdx.x;
    const int lane = tid & 63;
    const int wid  = tid >> 6;
    const int wm   = wid >> 1, wn = wid & 1;
    const int col  = lane & 15, quad = lane >> 4;
    const int bid  = blockIdx.x;
    const int r8   = bid & 7, q8 = bid >> 3;
    const int nbg  = r8 & 3;                     // pinned per XCD
    const int m0   = (q8 * 2 + (r8 >> 2)) * 128; // bijective token-tile map

    // preload all A fragments: af[mi][kb] (128 VGPRs), reused for 32 n-tiles
    short8 af[4][8];
#pragma unroll
    for (int mi = 0; mi < 4; ++mi) {
        const unsigned short* base =
            Xbf + (size_t)(m0 + wm * 64 + mi * 16 + col) * DIM + quad * 8;
#pragma unroll
        for (int kb = 0; kb < 8; ++kb)
            af[mi][kb] = *(const short8*)(base + kb * 32);
    }

    unsigned b1[16], b2[16];
#pragma unroll
    for (int i = 0; i < 16; ++i) { b1[i] = 0xFFFFFFFFu; b2[i] = 0xFFFFFFFFu; }

    // staging: source EbfT [tile128][kb:8192B][quad:2048B][half:1024B][n:16B];
    // 64-code subtile st: tile128 = st>>1, half = st&1. LDS dst linear
    // [kb][quad][n64]: unit u = i*256+tid -> kb=i, quad=tid>>6, n=tid&63.
    const char* gbase = (const char*)EbfT + (size_t)nbg * 16 * 65536 +
                        (tid >> 6) * 2048 + (tid & 63) * 16;
    char* ldst0 = (char*)Bs + tid * 16;

#define STAGE(st, b)                                                          \
    {                                                                         \
        const char* s_ = gbase + ((st) >> 1) * 65536 + ((st) & 1) * 1024;     \
        char* d_ = ldst0 + (b) * 32768;                                       \
        _Pragma("unroll")                                                     \
        for (int i_ = 0; i_ < 8; ++i_)                                        \
            gl_lds16(s_ + i_ * 8192, d_ + i_ * 4096);                         \
    }

    STAGE(0, 0);
    __syncthreads();
    int cur = 0;
    const int n_a = wn * 32 + col;
    const int n_b = wn * 32 + 16 + col;

    for (int st = 0; st < 32; ++st) {
        if (st < 31) STAGE(st + 1, cur ^ 1);   // prefetch next tile (other buf)

        const int n0 = nbg * 2048 + st * 64;
        float e0 = es2[n0 + n_a];
        float e1 = es2[n0 + n_b];
        floatx4 acc[4][2];
#pragma unroll
        for (int mi = 0; mi < 4; ++mi) {
            acc[mi][0] = (floatx4)e0;          // C-in carries ||e||^2 term
            acc[mi][1] = (floatx4)e1;
        }
        const unsigned short* B = &Bs[cur][0];
#pragma unroll
        for (int kb = 0; kb < 8; ++kb) {
            // 16B/lane, consecutive cols -> 2-way bank aliasing only (free)
            short8 bf0 = *(const short8*)&B[kb * 2048 + quad * 512 + n_a * 8];
            short8 bf1 = *(const short8*)&B[kb * 2048 + quad * 512 + n_b * 8];
#pragma unroll
            for (int mi = 0; mi < 4; ++mi) {
                acc[mi][0] = __builtin_amdgcn_mfma_f32_16x16x32_bf16(
                    af[mi][kb], bf0, acc[mi][0], 0, 0, 0);
                acc[mi][1] = __builtin_amdgcn_mfma_f32_16x16x32_bf16(
                    af[mi][kb], bf1, acc[mi][1], 0, 0, 0);
            }
        }
#pragma unroll
        for (int nj = 0; nj < 2; ++nj) {
            unsigned idxc = (unsigned)(n0 + wn * 32 + nj * 16 + col);
#pragma unroll
            for (int mi = 0; mi < 4; ++mi)
#pragma unroll
                for (int r = 0; r < 4; ++r) {
                    unsigned key = ((unsigned)acc[mi][nj][r] << 13) + idxc;
                    int s = mi * 4 + r;
                    unsigned lo = umin2(key, b1[s]);
                    unsigned hi = umax2(key, b1[s]);
                    b1[s] = lo;
                    b2[s] = umin2(hi, b2[s]);
                }
        }
        __syncthreads();                       // staged(st+1) landed; reads done
        cur ^= 1;
    }
#undef STAGE

#pragma unroll
    for (int mi = 0; mi < 4; ++mi)
#pragma unroll
        for (int r = 0; r < 4; ++r) {
            int token = m0 + wm * 64 + mi * 16 + quad * 4 + r;
            uint2 v; v.x = b1[mi * 4 + r]; v.y = b2[mi * 4 + r];
            *(uint2*)&cand[(size_t)token * NCAND + nbg * 64 + wn * 32 + col * 2] = v;
        }
}

// ---------------------------------------------------------------------------
// Fused exact fp32 rescore + quantize gather + cursor scatter.
// GROUP-PARALLEL rescore: each 16-lane group scores its own candidate (4 in
// flight per wave). Winner row re-gathered once at the end (L2-hot).
__global__ __launch_bounds__(256) void finalize_kernel(
    const float* __restrict__ x, const float* __restrict__ embedT,
    const float* __restrict__ e2,
    const unsigned int* __restrict__ cand,
    float* __restrict__ out,
    unsigned int* __restrict__ cnt,
    unsigned short* __restrict__ slots,
    float* __restrict__ diffp) {
    __shared__ float partial[4];
    int tid = threadIdx.x, w = tid >> 6, lane = tid & 63;
    int l16 = lane & 15, grp = lane >> 4;
    int token = blockIdx.x * 4 + w;

    float4 xv = *(const float4*)&x[(size_t)token * DIM + lane * 4];
    // replicated x row per 16-lane group (L1-hot reload of the same 1KB)
    float4 xg[4];
#pragma unroll
    for (int q = 0; q < 4; ++q)
        xg[q] = *(const float4*)&x[(size_t)token * DIM + q * 64 + l16 * 4];

    float x2 = xv.x * xv.x + xv.y * xv.y + xv.z * xv.z + xv.w * xv.w;
    uint4 c = *(const uint4*)&cand[(size_t)token * NCAND + lane * 4];
    unsigned g = umin2(umin2(c.x, c.y), umin2(c.z, c.w));
#pragma unroll
    for (int m = 1; m < 64; m <<= 1) {
        x2 += __shfl_xor(x2, m);
        g = umin2(g, (unsigned)__shfl_xor((int)g, m));
    }
    const unsigned thr = g + (384u << 13);   // margin 1.5 in true-dist units

    float bd = 3.4e38f; int bk = 0x7fffffff;
    unsigned ca[4] = {c.x, c.y, c.z, c.w};
#pragma unroll
    for (int s = 0; s < 4; ++s) {
        unsigned long long mask = __ballot(ca[s] <= thr);
        while (mask) {
            int kk[4];
#pragma unroll
            for (int g2 = 0; g2 < 4; ++g2) {
                int l = mask ? (__ffsll(mask) - 1) : 0;
                int kv = __shfl((int)ca[s], l) & 8191;
                kk[g2] = mask ? kv : -1;
                mask &= mask - 1;
            }
            int myk = kk[grp];
            int kc = myk < 0 ? 0 : myk;
            const float* er = &embedT[(size_t)kc * DIM];
            float p = 0.f;
#pragma unroll
            for (int q = 0; q < 4; ++q) {
                float4 ev = *(const float4*)&er[q * 64 + l16 * 4];
                p = fmaf(xg[q].x, ev.x, p);
                p = fmaf(xg[q].y, ev.y, p);
                p = fmaf(xg[q].z, ev.z, p);
                p = fmaf(xg[q].w, ev.w, p);
            }
#pragma unroll
            for (int m = 1; m < 16; m <<= 1) p += __shfl_xor(p, m);
            float dg = (myk >= 0) ? (e2[kc] - 2.0f * p) : 3.4e38f;
#pragma unroll
            for (int g2 = 0; g2 < 4; ++g2) {
                float d2 = __shfl(dg, g2 * 16);
                int k2 = kk[g2];
                if (k2 >= 0 && (d2 < bd || (d2 == bd && k2 < bk))) {
                    bd = d2; bk = k2;
                }
            }
        }
    }
    // winner row gather (1KB, L2-hot from the rescore) + outputs
    float4 bq = *(const float4*)&embedT[(size_t)bk * DIM + lane * 4];
    *(float4*)&out[OFF_Q + (size_t)token * DIM + lane * 4] = bq;
    if (lane == 0) {
        out[OFF_IND + token] = (float)bk;
        unsigned pos = atomicAdd(&cnt[bk], 1u);
        if (pos < CAP) slots[(size_t)bk * CAP + pos] = (unsigned short)token;
        partial[w] = x2 + bd;
    }
    __syncthreads();
    if (tid == 0)
        diffp[blockIdx.x] =
            partial[0] + partial[1] + partial[2] + partial[3];
}

// ---------------------------------------------------------------------------
// build_desc: >=1 chunk descriptor per code (n=0 codes get one empty chunk so
// embed_sum writes their zero rows -> the esT memset dispatch is deleted).
// Wave-batched allocation: 1 same-address atomic per WAVE = 128 total.
__global__ __launch_bounds__(256) void build_desc_kernel(
    const unsigned int* __restrict__ cnt,
    unsigned int* __restrict__ ndesc,
    unsigned int* __restrict__ desc) {
    int k = blockIdx.x * 256 + threadIdx.x;
    int lane = threadIdx.x & 63;
    unsigned n = cnt[k];
    unsigned nc = (n > CAP) ? 1u : umax2(1u, (n + CHUNK - 1) >> 6);
    unsigned pfx = nc;
#pragma unroll
    for (int m = 1; m < 64; m <<= 1) {
        unsigned t = __shfl_up(pfx, m);
        if (lane >= m) pfx += t;
    }
    unsigned base = 0;
    if (lane == 63) base = atomicAdd(ndesc, pfx);
    base = __shfl(base, 63);
    unsigned off = base + pfx - nc;
    for (unsigned j = 0; j < nc; ++j)
        desc[off + j] = (unsigned)k | (j << 13);
}

// ---------------------------------------------------------------------------
// embed_sum: one WAVE per 64-token chunk descriptor (balanced). 8-way ILP:
// 8 slot ids per uint4, 8 independent coalesced 1KB x-row loads in flight.
// n=0 chunks store a zero row (replaces the esT memset).
__global__ __launch_bounds__(256) void embed_sum_kernel(
    const float* __restrict__ x,
    const unsigned int* __restrict__ cnt,
    const unsigned short* __restrict__ slots,
    const unsigned int* __restrict__ ndesc,
    const unsigned int* __restrict__ desc,
    const float* __restrict__ out_ind,
    float* __restrict__ esT) {
    int tid = threadIdx.x, w = tid >> 6, lane = tid & 63;
    unsigned wv = blockIdx.x * 4 + w;
    if (wv >= *ndesc) return;
    unsigned dsc = desc[wv];
    int k = dsc & 8191;
    int j = dsc >> 13;
    unsigned n = cnt[k];
    float ax = 0.f, ay = 0.f, az = 0.f, aw = 0.f;

    if (n > CAP) {           // pathological overflow: exact full scan (j==0 only)
        for (int tok = 0; tok < NTOK; ++tok)
            if ((int)out_ind[tok] == k) {
                float4 v = *(const float4*)&x[(size_t)tok * DIM + lane * 4];
                ax += v.x; ay += v.y; az += v.z; aw += v.w;
            }
        *(float4*)&esT[(size_t)k * DIM + lane * 4] = make_float4(ax, ay, az, aw);
        return;
    }

    int base = j * CHUNK;
    int nt = (int)n - base; if (nt > CHUNK) nt = CHUNK;
    const unsigned short* sl = &slots[(size_t)k * CAP + base];
    for (int gr = 0; gr < CHUNK; gr += 8) {
        if (gr >= nt) break;
        uint4 sv = *(const uint4*)(sl + gr);        // 8 slot ids, 16B aligned
        unsigned id[8] = {sv.x & 0xffffu, sv.x >> 16, sv.y & 0xffffu, sv.y >> 16,
                          sv.z & 0xffffu, sv.z >> 16, sv.w & 0xffffu, sv.w >> 16};
        float4 v[8];
#pragma unroll
        for (int i = 0; i < 8; ++i) {
            unsigned tok = (gr + i < nt) ? id[i] : id[0];  // clamp tail in-bounds
            v[i] = *(const float4*)&x[(size_t)tok * DIM + lane * 4];
        }
#pragma unroll
        for (int i = 0; i < 8; ++i)
            if (gr + i < nt) { ax += v[i].x; ay += v[i].y; az += v[i].z; aw += v[i].w; }
    }

    float* dst = &esT[(size_t)k * DIM + lane * 4];
    if (n <= CHUNK) {
        *(float4*)dst = make_float4(ax, ay, az, aw);   // n==0 writes zeros
    } else {
        atomicAdd(dst + 0, ax); atomicAdd(dst + 1, ay);
        atomicAdd(dst + 2, az); atomicAdd(dst + 3, aw);
    }
}

// ---------------------------------------------------------------------------
// es_out: transposed ES write + OH from cnt + DIFF reduction (block 0).
__global__ void es_out_kernel(const float* __restrict__ esT,
                              const unsigned int* __restrict__ cnt,
                              const float* __restrict__ diffp,
                              float* __restrict__ out) {
    __shared__ __align__(16) float t2[32][DIM + 4];
    __shared__ float rsum[256];
    int k0 = blockIdx.x * 32;
    int tid = threadIdx.x;
    for (int t = 0; t < 8; ++t) {
        int i = t * 256 + tid;          // float4 units over 32x256
        int k = i >> 6, dq = i & 63;
        float4 v = ((const float4*)esT)[(size_t)(k0 + k) * 64 + dq];
        *(float4*)&t2[k][dq * 4] = v;
    }
    __syncthreads();
    for (int t = 0; t < 32; ++t) {
        int i = t * 256 + tid;          // 8192 cells
        int d = i >> 5, c = i & 31;
        out[OFF_ES + (size_t)d * NE + k0 + c] = t2[c][d];
    }
    if (tid < 32) out[OFF_OH + k0 + tid] = (float)cnt[k0 + tid];
    if (blockIdx.x == 0) {              // DIFF: reduce 4096 per-block partials
        float s = 0.f;
        for (int i = tid; i < NTOK / 4; i += 256) s += diffp[i];
        rsum[tid] = s;
        __syncthreads();
        for (int st = 128; st > 0; st >>= 1) {
            if (tid < st) rsum[tid] += rsum[tid + st];
            __syncthreads();
        }
        if (tid == 0) out[OFF_DIFF] = rsum[0] * (1.0f / 4194304.0f);
    }
}

// ===========================================================================
extern "C" void kernel_launch(void* const* d_in, const int* in_sizes, int n_in,
                              void* d_out, int out_size, void* d_ws, size_t ws_size,
                              hipStream_t stream) {
    const float* x     = (const float*)d_in[0];
    const float* embed = (const float*)d_in[1];
    float* out = (float*)d_out;

    // ws layout (~54.8 MB). esT ALIASES Xbf (both exactly 8.4 MB): Xbf is dead
    // after dist_screen; embed_sum (after finalize in stream order) overwrites
    // every row, so no memset and no hazard.
    char* p = (char*)d_ws;
    unsigned short* Xbf  = (unsigned short*)p;  p += (size_t)NTOK * DIM * 2;    // 8.4 MB
    float* esT = (float*)Xbf;                                                   // alias
    unsigned short* EbfT = (unsigned short*)p;  p += (size_t)NE * DIM * 2;      // 4.2 MB (tiled)
    float* embedT = (float*)p;                  p += (size_t)NE * DIM * 4;      // 8.4 MB
    float* e2     = (float*)p;                  p += (size_t)NE * 4;
    float* es2    = (float*)p;                  p += (size_t)NE * 4;
    unsigned int* cand = (unsigned int*)p;      p += (size_t)NTOK * NCAND * 4;  // 16.8 MB
    unsigned int* cnt  = (unsigned int*)p;      p += (size_t)NE * 4;            // 32 KB
    unsigned int* ndesc = (unsigned int*)p;     p += 64;                        // (memset w/ cnt)
    unsigned int* desc = (unsigned int*)p;      p += (size_t)(DESC_MAX + 64) * 4;
    float* diffp = (float*)p;                   p += (size_t)(NTOK / 4) * 4;    // 16 KB
    unsigned short* slots = (unsigned short*)p; p += (size_t)NE * CAP * 2;      // 16.8 MB

    // cnt + ndesc zeroed; d_out header needs no memset (DIFF/IND/OH/Q/ES all
    // fully written every launch: IND by finalize, OH+DIFF by es_out).
    hipMemsetAsync(cnt, 0, (size_t)NE * 4 + 64, stream);

    convert_kernel<<<4096 + NE / 32, 256, 0, stream>>>(
        x, Xbf, embed, EbfT, embedT, e2, es2);
    dist_screen_kernel<<<512, 256, 0, stream>>>(Xbf, EbfT, es2, cand);
    finalize_kernel<<<NTOK / 4, 256, 0, stream>>>(
        x, embedT, e2, cand, out, cnt, slots, diffp);
    build_desc_kernel<<<NE / 256, 256, 0, stream>>>(cnt, ndesc, desc);
    embed_sum_kernel<<<DESC_MAX / 4, 256, 0, stream>>>(
        x, cnt, slots, ndesc, desc, out + OFF_IND, esT);
    es_out_kernel<<<NE / 32, 256, 0, stream>>>(esT, cnt, diffp, out);
}